// Round 6
// baseline (297.642 us; speedup 1.0000x reference)
//
#include <hip/hip_runtime.h>
#include <math.h>

typedef __attribute__((ext_vector_type(8))) short short8;
typedef __attribute__((ext_vector_type(4))) float f32x4;

#define NN 10000
#define EE 320000
#define NHEAD 16
#define EPSf 1e-5f

// ---------- bf16 helpers ----------
__device__ __forceinline__ unsigned short f2bf(float f) {
    union { float f; unsigned u; } v; v.f = f;
    unsigned u = v.u;
    u += 0x7fffu + ((u >> 16) & 1u);   // RNE
    return (unsigned short)(u >> 16);
}
__device__ __forceinline__ unsigned pk2(float a, float b) {
    return ((unsigned)f2bf(b) << 16) | (unsigned)f2bf(a);
}

// sEX/sVl overlays on Y's k-half (rows 0..15 / 16..31), half-index addressing
__device__ __forceinline__ float& sEXat(unsigned short* sR, int ix) {
    return *(float*)(sR + ((ix >> 6) << 8) + ((ix & 63) << 1));
}
__device__ __forceinline__ float& sVLat(unsigned short* sR, int ix) {
    return *(float*)(sR + 4096 + ((ix >> 6) << 8) + ((ix & 63) << 1));
}

// ---------------------- init: cnt/0, D/0, P/0 ----------------------
__global__ void k_init0(int* __restrict__ cnt, float* __restrict__ Dg,
                        float* __restrict__ Pg) {
    int i = blockIdx.x * 256 + threadIdx.x;
    if (i < NN) cnt[i] = 0;
    if (i < NN * 16) Dg[i] = 0.f;
    if (i < NN * 48) Pg[i] = 0.f;
}

// ---------- fused: hist (1250 blocks) + prep (5424) + qmlp (313) ----------
#define PRE_HIST 1250
#define PRE_PREP 5424
#define PRE_QMLP 313
__global__ __launch_bounds__(256) void k_pre(
    const int* __restrict__ ei, int* __restrict__ cnt,
    const float* __restrict__ h,
    const float* __restrict__ kW1, const float* __restrict__ vW1,
    const float* __restrict__ kW2, const float* __restrict__ vW2,
    unsigned short* __restrict__ h_bf, unsigned short* __restrict__ Wt1,
    unsigned short* __restrict__ kW2t, unsigned short* __restrict__ vW2t,
    const float* __restrict__ qW1, const float* __restrict__ qb1,
    const float* __restrict__ qg,  const float* __restrict__ qbt,
    const float* __restrict__ qW2, const float* __restrict__ qb2,
    float* __restrict__ qout)
{
    __shared__ float sU[8192];
    const int tid = threadIdx.x;
    int b = blockIdx.x;

    if (b < PRE_HIST) {                       // ---- histogram role ----
        int e = b * 256 + tid;                // EE = 1250*256 exactly
        atomicAdd(&cnt[ei[EE + e]], 1);
        return;
    }
    b -= PRE_HIST;
    if (b < PRE_PREP) {                       // ---- prep role ----
        int i = b * 256 + tid;
        if (i < NN * 128) { h_bf[i] = f2bf(h[i]); return; }
        int j = i - NN * 128;
        if (j < 256 * 352) {
            int n = j / 352, k = j % 352;
            float val = 0.f;
            if (k < 340) {
                int pk;
                if (k < 128)      pk = 84 + k;
                else if (k < 256) pk = 212 + (k - 128);
                else if (k < 260) pk = k - 256;
                else              pk = 4 + (k - 260);
                val = (n < 128) ? kW1[pk * 128 + n] : vW1[pk * 128 + (n - 128)];
            }
            Wt1[j] = f2bf(val); return;
        }
        j -= 256 * 352;
        if (j < 128 * 128) { int n = j >> 7, k = j & 127; kW2t[j] = f2bf(kW2[k * 128 + n]); return; }
        j -= 128 * 128;
        if (j < 16 * 128)  { int n = j >> 7, k = j & 127; vW2t[j] = f2bf(vW2[k * 16 + n]); return; }
        return;
    }
    b -= PRE_PREP;                            // ---- qmlp role ----
    float* sH = sU;
    float* sY = sU + 4096;
    const int n0 = b * 32;

    #pragma unroll
    for (int j = 0; j < 4; ++j) {
        int p = tid + j * 256;
        int e = p >> 5, i = p & 31;
        int node = n0 + e; if (node >= NN) node = NN - 1;
        float4 v = *(const float4*)(h + node * 128 + i * 4);
        *(float4*)(sH + e * 128 + i * 4) = v;
    }
    __syncthreads();

    const int c  = tid & 127;
    const int eg = (tid >> 7) * 16;
    float acc[16];
    #pragma unroll
    for (int e = 0; e < 16; ++e) acc[e] = 0.f;
    for (int k = 0; k < 128; k += 4) {
        float w0 = qW1[(k + 0) * 128 + c], w1 = qW1[(k + 1) * 128 + c];
        float w2 = qW1[(k + 2) * 128 + c], w3 = qW1[(k + 3) * 128 + c];
        #pragma unroll
        for (int e = 0; e < 16; ++e) {
            float4 a = *(const float4*)(sH + (eg + e) * 128 + k);
            acc[e] += a.x * w0 + a.y * w1 + a.z * w2 + a.w * w3;
        }
    }
    {
        float bb = qb1[c];
        #pragma unroll
        for (int e = 0; e < 16; ++e) sY[(eg + e) * 128 + c] = acc[e] + bb;
    }
    __syncthreads();

    {
        int r = tid >> 3, s = tid & 7;
        float* row = sY + r * 128;
        float vals[16];
        float sum = 0.f, sq = 0.f;
        #pragma unroll
        for (int j = 0; j < 4; ++j) {
            float4 v = *(float4*)(row + s * 16 + j * 4);
            vals[j*4+0] = v.x; vals[j*4+1] = v.y; vals[j*4+2] = v.z; vals[j*4+3] = v.w;
        }
        #pragma unroll
        for (int j = 0; j < 16; ++j) { sum += vals[j]; sq += vals[j] * vals[j]; }
        #pragma unroll
        for (int o = 1; o < 8; o <<= 1) { sum += __shfl_xor(sum, o, 64); sq += __shfl_xor(sq, o, 64); }
        float mu = sum * (1.f / 128.f);
        float var = sq * (1.f / 128.f) - mu * mu;
        float rs = rsqrtf(var + EPSf);
        #pragma unroll
        for (int j = 0; j < 16; ++j) {
            int col = s * 16 + j;
            float a = (vals[j] - mu) * rs * qg[col] + qbt[col];
            row[col] = a > 0.f ? a : 0.f;
        }
    }
    __syncthreads();

    #pragma unroll
    for (int e = 0; e < 16; ++e) acc[e] = 0.f;
    for (int k = 0; k < 128; k += 4) {
        float w0 = qW2[(k + 0) * 128 + c], w1 = qW2[(k + 1) * 128 + c];
        float w2 = qW2[(k + 2) * 128 + c], w3 = qW2[(k + 3) * 128 + c];
        #pragma unroll
        for (int e = 0; e < 16; ++e) {
            float4 a = *(const float4*)(sY + (eg + e) * 128 + k);
            acc[e] += a.x * w0 + a.y * w1 + a.z * w2 + a.w * w3;
        }
    }
    {
        float bb = qb2[c];
        #pragma unroll
        for (int e = 0; e < 16; ++e) {
            int node = n0 + eg + e;
            if (node < NN) qout[node * 128 + c] = acc[e] + bb;
        }
    }
}

// ---------------------- scan (wave-based, 2 barriers) ----------------------
__global__ __launch_bounds__(1024) void k_scan(const int* __restrict__ cnt,
                                               int* __restrict__ cnt2) {
    __shared__ int wsum[16];
    const int t = threadIdx.x;
    const int lane = t & 63, w = t >> 6;
    int loc[10];
    int s = 0;
    #pragma unroll
    for (int i = 0; i < 10; ++i) {
        int idx = t * 10 + i;
        loc[i] = (idx < NN) ? cnt[idx] : 0;
        s += loc[i];
    }
    int sc = s;   // inclusive wave scan
    #pragma unroll
    for (int off = 1; off < 64; off <<= 1) {
        int v = __shfl_up(sc, off, 64);
        if (lane >= off) sc += v;
    }
    if (lane == 63) wsum[w] = sc;
    __syncthreads();
    if (w == 0) {
        int v = (lane < 16) ? wsum[lane] : 0;
        int c = v;
        #pragma unroll
        for (int off = 1; off < 16; off <<= 1) {
            int t2 = __shfl_up(c, off, 64);
            if (lane >= off) c += t2;
        }
        if (lane < 16) wsum[lane] = c - v;   // exclusive
    }
    __syncthreads();
    int run = wsum[w] + sc - s;
    #pragma unroll
    for (int i = 0; i < 10; ++i) {
        int idx = t * 10 + i;
        if (idx < NN) { cnt2[idx] = run; run += loc[i]; }
    }
}

__global__ void k_place(const int* __restrict__ ei, int* __restrict__ cnt2,
                        int* __restrict__ perm) {
    int e = blockIdx.x * 256 + threadIdx.x;
    if (e < EE) {
        int slot = atomicAdd(&cnt2[ei[EE + e]], 1);
        perm[slot] = e;
    }
}

// ------- per-slot MFMA kernel: 2-phase staging (32KB LDS), fused epilogue -------
__global__ __launch_bounds__(256, 4) void k_edge(
    const float* __restrict__ x, const unsigned short* __restrict__ h_bf,
    const float* __restrict__ ea, const int* __restrict__ ei,
    const int* __restrict__ perm,
    const unsigned short* __restrict__ Wt1,
    const float* __restrict__ kb1, const float* __restrict__ vb1,
    const float* __restrict__ kg, const float* __restrict__ kbt,
    const float* __restrict__ vg, const float* __restrict__ vbt,
    const unsigned short* __restrict__ kW2t, const float* __restrict__ kb2,
    const unsigned short* __restrict__ vW2t, const float* __restrict__ vb2,
    const float* __restrict__ q,
    float* __restrict__ Dg, float* __restrict__ Pg)
{
    // sR (32KB) time-multiplexed:
    //   staging buf [64 rows][24 chunks] (24.6KB, swizzled)  ->  Y [64][32 chunks]
    //   then sEX/sVl overlay Y k-half rows 0..31 after L2k barrier
    __shared__ __align__(16) unsigned short sR[64 * 256];
    __shared__ float2 sStats[4 * 64];
    __shared__ float sEA[64 * 4];
    __shared__ float sRel[64 * 3];
    __shared__ float sDist[64];
    __shared__ int   sSrc[64], sDst[64];

    const int tid  = threadIdx.x;
    const int e0   = blockIdx.x * 64;
    const int lane = tid & 63;
    const int wv   = tid >> 6;
    const int rA   = lane & 15;
    const int kq   = lane >> 4;

    if (tid < 64) {
        int slot = e0 + tid;
        int e = perm[slot];
        int s = ei[e], d = ei[EE + e];
        sSrc[tid] = s; sDst[tid] = d;
        float rx = x[d*3+0] - x[s*3+0];
        float ry = x[d*3+1] - x[s*3+1];
        float rz = x[d*3+2] - x[s*3+2];
        sRel[tid*3+0] = rx; sRel[tid*3+1] = ry; sRel[tid*3+2] = rz;
        sDist[tid] = sqrtf(rx*rx + ry*ry + rz*rz);
        float4 eav = *(const float4*)(ea + e * 4);
        sEA[tid*4+0] = eav.x; sEA[tid*4+1] = eav.y;
        sEA[tid*4+2] = eav.z; sEA[tid*4+3] = eav.w;
    }
    __syncthreads();

    // ---- stage phase 1: k' 0..191 (h_dst cc0..15 -> cl0..15, h_src cc0..7 -> cl16..23)
    #pragma unroll
    for (int it = 0; it < 6; ++it) {
        int p = tid + it * 256;           // 0..1535
        int r = p / 24, cl = p % 24;
        int node = (cl < 16) ? sDst[r] : sSrc[r];
        int cc = cl & 15;
        uint4 v = *(const uint4*)(h_bf + node * 128 + cc * 8);
        *(uint4*)(sR + r * 192 + ((cl ^ (r & 7)) << 3)) = v;
    }
    __syncthreads();

    // ---- layer 1, phase A: k0 = 0..191 ----
    const int n0 = wv * 64;
    f32x4 zf = {0.f, 0.f, 0.f, 0.f};
    f32x4 acc[4][4];   // [nf][ef]
    #pragma unroll
    for (int nf = 0; nf < 4; ++nf)
        #pragma unroll
        for (int ef = 0; ef < 4; ++ef) acc[nf][ef] = zf;

    for (int k0 = 0; k0 < 192; k0 += 32) {
        int clb = (k0 >> 3) + kq;
        short8 wfr[4], kv[4];
        #pragma unroll
        for (int nf = 0; nf < 4; ++nf)
            wfr[nf] = *(const short8*)(Wt1 + (n0 + nf * 16 + rA) * 352 + k0 + kq * 8);
        #pragma unroll
        for (int ef = 0; ef < 4; ++ef) {
            int r = ef * 16 + rA;
            kv[ef] = *(const short8*)(sR + r * 192 + ((clb ^ (r & 7)) << 3));
        }
        #pragma unroll
        for (int nf = 0; nf < 4; ++nf)
            #pragma unroll
            for (int ef = 0; ef < 4; ++ef)
                acc[nf][ef] = __builtin_amdgcn_mfma_f32_16x16x32_bf16(wfr[nf], kv[ef], acc[nf][ef], 0, 0, 0);
    }
    __syncthreads();   // all reads of phase-1 buffer done

    // ---- stage phase 2: h_src cc8..15 -> cl0..7 ; ea+dist (i 0..95) -> cl8..19
    #pragma unroll
    for (int it = 0; it < 2; ++it) {
        int p = tid + it * 256;           // 0..511
        int r = p >> 3, cl = p & 7;
        uint4 v = *(const uint4*)(h_bf + sSrc[r] * 128 + (8 + cl) * 8);
        *(uint4*)(sR + r * 192 + ((cl ^ (r & 7)) << 3)) = v;
    }
    const float step  = 10.0f / 19.0f;
    const float coeff = -0.5f / (step * step);
    #pragma unroll
    for (int it = 0; it < 6; ++it) {
        int q4 = tid + it * 256;          // 0..1535 quads
        int r = q4 / 24, qi = q4 % 24;
        int i0 = qi * 4;
        float v[4];
        #pragma unroll
        for (int j = 0; j < 4; ++j) {
            int i = i0 + j;
            float val;
            if (i < 4) val = sEA[r*4 + i];
            else if (i < 84) {
                int f = (i - 4) / 20, gg = (i - 4) % 20;
                float dd = sDist[r] - (float)gg * step;
                val = sEA[r*4 + f] * __expf(coeff * dd * dd);
            } else val = 0.f;
            v[j] = val;
        }
        int cl = 8 + (i0 >> 3);
        uint2 pw; pw.x = pk2(v[0], v[1]); pw.y = pk2(v[2], v[3]);
        *(uint2*)(sR + r * 192 + ((cl ^ (r & 7)) << 3) + (i0 & 7)) = pw;
    }
    __syncthreads();

    // ---- layer 1, phase B: k0 = 192..351 ----
    for (int k0 = 192; k0 < 352; k0 += 32) {
        int clb = ((k0 - 192) >> 3) + kq;
        short8 wfr[4], kv[4];
        #pragma unroll
        for (int nf = 0; nf < 4; ++nf)
            wfr[nf] = *(const short8*)(Wt1 + (n0 + nf * 16 + rA) * 352 + k0 + kq * 8);
        #pragma unroll
        for (int ef = 0; ef < 4; ++ef) {
            int r = ef * 16 + rA;
            kv[ef] = *(const short8*)(sR + r * 192 + ((clb ^ (r & 7)) << 3));
        }
        #pragma unroll
        for (int nf = 0; nf < 4; ++nf)
            #pragma unroll
            for (int ef = 0; ef < 4; ++ef)
                acc[nf][ef] = __builtin_amdgcn_mfma_f32_16x16x32_bf16(wfr[nf], kv[ef], acc[nf][ef], 0, 0, 0);
    }

    // ---- bias add (before LN stats) ----
    {
        const float* bsrc = (wv < 2) ? kb1 : vb1;
        int cb = (wv & 1) * 64;
        #pragma unroll
        for (int nf = 0; nf < 4; ++nf) {
            f32x4 bb = *(const f32x4*)(bsrc + cb + nf * 16 + kq * 4);
            #pragma unroll
            for (int ef = 0; ef < 4; ++ef)
                #pragma unroll
                for (int j = 0; j < 4; ++j) acc[nf][ef][j] += bb[j];
        }
    }

    // ---- in-register LN stats ----
    float sm[4], sq2[4];
    #pragma unroll
    for (int ef = 0; ef < 4; ++ef) {
        float s = 0.f, s2 = 0.f;
        #pragma unroll
        for (int nf = 0; nf < 4; ++nf)
            #pragma unroll
            for (int j = 0; j < 4; ++j) { float v = acc[nf][ef][j]; s += v; s2 += v * v; }
        sm[ef] = s; sq2[ef] = s2;
    }
    #pragma unroll
    for (int ef = 0; ef < 4; ++ef) {
        sm[ef]  += __shfl_xor(sm[ef], 16, 64);  sm[ef]  += __shfl_xor(sm[ef], 32, 64);
        sq2[ef] += __shfl_xor(sq2[ef], 16, 64); sq2[ef] += __shfl_xor(sq2[ef], 32, 64);
    }
    if (kq == 0) {
        #pragma unroll
        for (int ef = 0; ef < 4; ++ef)
            sStats[wv * 64 + ef * 16 + rA] = make_float2(sm[ef], sq2[ef]);
    }
    __syncthreads();   // stats ready AND all phase-B reads done

    // ---- normalize + ReLU + pack -> Y (row stride 256 halves, swizzled) ----
    {
        const float* gp = (wv < 2) ? kg : vg;
        const float* bp = (wv < 2) ? kbt : vbt;
        f32x4 g4[4], b4[4];
        #pragma unroll
        for (int nf = 0; nf < 4; ++nf) {
            int cl = (wv & 1) * 64 + nf * 16 + kq * 4;
            g4[nf] = *(const f32x4*)(gp + cl);
            b4[nf] = *(const f32x4*)(bp + cl);
        }
        #pragma unroll
        for (int ef = 0; ef < 4; ++ef) {
            int e = ef * 16 + rA;
            float2 po = sStats[(wv ^ 1) * 64 + e];
            float mu  = (sm[ef] + po.x) * (1.f / 128.f);
            float var = (sq2[ef] + po.y) * (1.f / 128.f) - mu * mu;
            float rs  = rsqrtf(var + EPSf);
            #pragma unroll
            for (int nf = 0; nf < 4; ++nf) {
                float y[4];
                #pragma unroll
                for (int j = 0; j < 4; ++j) {
                    float f = (acc[nf][ef][j] - mu) * rs * g4[nf][j] + b4[nf][j];
                    y[j] = f > 0.f ? f : 0.f;
                }
                int col = n0 + nf * 16 + kq * 4;
                int ch = col >> 3;
                uint2 pw; pw.x = pk2(y[0], y[1]); pw.y = pk2(y[2], y[3]);
                *(uint2*)(sR + e * 256 + ((ch ^ (e & 7)) << 3) + (col & 7)) = pw;
            }
        }
    }
    __syncthreads();

    // ---- layer 2 (k) + logits (ps kept in regs; sEX written after barrier) ----
    float ps[2][4];
    int dloc[4];
    {
        const int n0k = wv * 32;
        f32x4 a2[2][4];
        #pragma unroll
        for (int nf2 = 0; nf2 < 2; ++nf2)
            #pragma unroll
            for (int ef = 0; ef < 4; ++ef) a2[nf2][ef] = zf;
        for (int k0 = 0; k0 < 128; k0 += 32) {
            int cbase = (k0 >> 3) + kq;
            short8 wf2[2], yf[4];
            #pragma unroll
            for (int nf2 = 0; nf2 < 2; ++nf2)
                wf2[nf2] = *(const short8*)(kW2t + (n0k + nf2 * 16 + rA) * 128 + k0 + kq * 8);
            #pragma unroll
            for (int ef = 0; ef < 4; ++ef) {
                int r = ef * 16 + rA;
                yf[ef] = *(const short8*)(sR + r * 256 + ((cbase ^ (r & 7)) << 3));
            }
            #pragma unroll
            for (int nf2 = 0; nf2 < 2; ++nf2)
                #pragma unroll
                for (int ef = 0; ef < 4; ++ef)
                    a2[nf2][ef] = __builtin_amdgcn_mfma_f32_16x16x32_bf16(wf2[nf2], yf[ef], a2[nf2][ef], 0, 0, 0);
        }
        f32x4 bb2[2];
        bb2[0] = *(const f32x4*)(kb2 + n0k + kq * 4);
        bb2[1] = *(const f32x4*)(kb2 + n0k + 16 + kq * 4);
        #pragma unroll
        for (int ef = 0; ef < 4; ++ef) dloc[ef] = sDst[ef * 16 + rA];

        #pragma unroll
        for (int nf2 = 0; nf2 < 2; ++nf2)
            #pragma unroll
            for (int ef = 0; ef < 4; ++ef) {
                const float* qn = q + dloc[ef] * 128 + n0k + nf2 * 16 + kq * 4;
                f32x4 qv = *(const f32x4*)qn;
                float s = 0.f;
                #pragma unroll
                for (int j = 0; j < 4; ++j) s += qv[j] * (a2[nf2][ef][j] + bb2[nf2][j]);
                ps[nf2][ef] = s;
            }
        #pragma unroll
        for (int nf2 = 0; nf2 < 2; ++nf2)
            #pragma unroll
            for (int ef = 0; ef < 4; ++ef)
                ps[nf2][ef] += __shfl_xor(ps[nf2][ef], 16, 64);
    }
    __syncthreads();   // all Y k-half reads done -> safe to overlay sEX/sVl

    // ---- write sEX; layer 2 (v) -> sVl (reads Y v-half, disjoint) ----
    {
        int h_base = wv * 4 + (kq >> 1);
        #pragma unroll
        for (int nf2 = 0; nf2 < 2; ++nf2)
            #pragma unroll
            for (int ef = 0; ef < 4; ++ef) {
                bool act = ((kq & 1) == 0) ? (ef < 2) : (ef >= 2);
                if (act) {
                    int e = ef * 16 + rA;
                    int hh = h_base + nf2 * 2;
                    sEXat(sR, hh * 64 + e) = __expf(ps[nf2][ef] * 0.35355339059327373f);
                }
            }
    }
    {
        f32x4 av = zf;
        int r = wv * 16 + rA;
        for (int k0 = 0; k0 < 128; k0 += 32) {
            int cbase = 16 + (k0 >> 3) + kq;
            short8 yv  = *(const short8*)(sR + r * 256 + ((cbase ^ (r & 7)) << 3));
            short8 wfv = *(const short8*)(vW2t + rA * 128 + k0 + kq * 8);
            av = __builtin_amdgcn_mfma_f32_16x16x32_bf16(wfv, yv, av, 0, 0, 0);
        }
        f32x4 bv = *(const f32x4*)(vb2 + kq * 4);
        #pragma unroll
        for (int j = 0; j < 4; ++j)
            sVLat(sR, (kq * 4 + j) * 64 + r) = av[j] + bv[j];
    }
    __syncthreads();

    // ---- segmented scan over 16-slot windows; atomics only at segment ends ----
    {
        const int s    = lane & 15;
        const int quad = lane >> 4;
        const int slot = wv * 16 + s;
        const int node = sDst[slot];

        bool fl = (s == 0) || (sDst[slot] != sDst[slot - 1]);
        unsigned long long bal = __ballot(fl);
        unsigned fb = (unsigned)((bal >> (quad * 16)) & 0xFFFFull);

        unsigned pre = fb & ((2u << s) - 1);
        int sstart = 31 - __clz(pre);

        float rx = sRel[slot * 3 + 0], ry = sRel[slot * 3 + 1], rz = sRel[slot * 3 + 2];
        float ex4[4], px[4], py[4], pz[4];
        #pragma unroll
        for (int j = 0; j < 4; ++j) {
            float exv = sEXat(sR, (quad * 4 + j) * 64 + slot);
            float vv  = sVLat(sR, (quad * 4 + j) * 64 + slot);
            float m = exv * vv;
            ex4[j] = exv; px[j] = m * rx; py[j] = m * ry; pz[j] = m * rz;
        }
        #pragma unroll
        for (int st = 1; st <= 8; st <<= 1) {
            bool take = (s - st >= sstart);
            #pragma unroll
            for (int j = 0; j < 4; ++j) {
                float t0 = __shfl_up(ex4[j], st, 16);
                float t1 = __shfl_up(px[j],  st, 16);
                float t2 = __shfl_up(py[j],  st, 16);
                float t3 = __shfl_up(pz[j],  st, 16);
                if (take) { ex4[j] += t0; px[j] += t1; py[j] += t2; pz[j] += t3; }
            }
        }
        bool isend = (s == 15) || ((fb >> (s + 1)) & 1u);
        if (isend) {
            #pragma unroll
            for (int j = 0; j < 4; ++j) {
                int hh = quad * 4 + j;
                atomicAdd(&Dg[node * 16 + hh], ex4[j]);
                atomicAdd(&Pg[node * 48 + 0 * 16 + hh], px[j]);
                atomicAdd(&Pg[node * 48 + 1 * 16 + hh], py[j]);
                atomicAdd(&Pg[node * 48 + 2 * 16 + hh], pz[j]);
            }
        }
    }
}

// ---------------------- finalize: out = (1/16) sum_h P/D ----------------------
__global__ void k_fin(const float* __restrict__ Dg, const float* __restrict__ Pg,
                      float* __restrict__ out) {
    int n = blockIdx.x * 256 + threadIdx.x;
    if (n >= NN) return;
    float inv[16];
    #pragma unroll
    for (int hq = 0; hq < 4; ++hq) {
        f32x4 d = *(const f32x4*)(Dg + n * 16 + hq * 4);
        #pragma unroll
        for (int j = 0; j < 4; ++j) inv[hq * 4 + j] = (d[j] > 0.f) ? (1.f / d[j]) : 0.f;
    }
    #pragma unroll
    for (int c = 0; c < 3; ++c) {
        float s = 0.f;
        #pragma unroll
        for (int hq = 0; hq < 4; ++hq) {
            f32x4 p = *(const f32x4*)(Pg + n * 48 + c * 16 + hq * 4);
            #pragma unroll
            for (int j = 0; j < 4; ++j) s += p[j] * inv[hq * 4 + j];
        }
        out[n * 3 + c] = s * (1.f / 16.f);
    }
}

extern "C" void kernel_launch(void* const* d_in, const int* in_sizes, int n_in,
                              void* d_out, int out_size, void* d_ws, size_t ws_size,
                              hipStream_t stream) {
    const float* x   = (const float*)d_in[0];
    const float* h   = (const float*)d_in[1];
    const float* ea  = (const float*)d_in[2];
    const int*   ei  = (const int*)d_in[4];
    const float* kW1 = (const float*)d_in[5];
    const float* kb1 = (const float*)d_in[6];
    const float* kg  = (const float*)d_in[7];
    const float* kbt = (const float*)d_in[8];
    const float* kW2 = (const float*)d_in[9];
    const float* kb2 = (const float*)d_in[10];
    const float* vW1 = (const float*)d_in[11];
    const float* vb1 = (const float*)d_in[12];
    const float* vg  = (const float*)d_in[13];
    const float* vbt = (const float*)d_in[14];
    const float* vW2 = (const float*)d_in[15];
    const float* vb2 = (const float*)d_in[16];
    const float* qW1 = (const float*)d_in[17];
    const float* qb1 = (const float*)d_in[18];
    const float* qg  = (const float*)d_in[19];
    const float* qbt = (const float*)d_in[20];
    const float* qW2 = (const float*)d_in[21];
    const float* qb2 = (const float*)d_in[22];

    float* ws = (float*)d_ws;
    float* qbuf = ws;                            // N*128 = 1,280,000 w
    float* Dg   = ws + 1280000;                  // N*16
    float* Pg   = ws + 1440000;                  // N*48
    unsigned short* h_bf = (unsigned short*)(ws + 1920000);   // N*128 halves
    unsigned short* Wt1  = (unsigned short*)(ws + 2560000);   // 256*352 halves
    unsigned short* kW2t = (unsigned short*)(ws + 2605056);   // 128*128 halves
    unsigned short* vW2t = (unsigned short*)(ws + 2613248);   // 16*128 halves
    int* cnt  = (int*)(ws + 2614272);            // N
    int* cnt2 = (int*)(ws + 2634273);            // N
    int* perm = (int*)(ws + 2644273);            // E
    float* out = (float*)d_out;

    hipLaunchKernelGGL(k_init0, dim3(1875), dim3(256),  0, stream, cnt, Dg, Pg);
    hipLaunchKernelGGL(k_pre,   dim3(PRE_HIST + PRE_PREP + PRE_QMLP), dim3(256), 0, stream,
                       ei, cnt, h, kW1, vW1, kW2, vW2, h_bf, Wt1, kW2t, vW2t,
                       qW1, qb1, qg, qbt, qW2, qb2, qbuf);
    hipLaunchKernelGGL(k_scan,  dim3(1),    dim3(1024), 0, stream, cnt, cnt2);
    hipLaunchKernelGGL(k_place, dim3(1250), dim3(256),  0, stream, ei, cnt2, perm);
    hipLaunchKernelGGL(k_edge,  dim3(5000), dim3(256),  0, stream,
                       x, h_bf, ea, ei, perm, Wt1,
                       kb1, vb1, kg, kbt, vg, vbt,
                       kW2t, kb2, vW2t, vb2,
                       qbuf, Dg, Pg);
    hipLaunchKernelGGL(k_fin,   dim3(40),   dim3(256),  0, stream, Dg, Pg, out);
}

// Round 7
// 230.937 us; speedup vs baseline: 1.2888x; 1.2888x over previous
//
#include <hip/hip_runtime.h>
#include <hip/hip_bf16.h>
#include <math.h>

typedef __attribute__((ext_vector_type(8))) short short8;
typedef __attribute__((ext_vector_type(4))) float f32x4;

#define NN 10000
#define EE 320000
#define NHEAD 16
#define EPSf 1e-5f

// ---------- bf16 helpers ----------
__device__ __forceinline__ unsigned short f2bf(float f) {
    union { float f; unsigned u; } v; v.f = f;
    unsigned u = v.u;
    u += 0x7fffu + ((u >> 16) & 1u);   // RNE
    return (unsigned short)(u >> 16);
}
__device__ __forceinline__ unsigned pk2(float a, float b) {
    __hip_bfloat162 t = __float22bfloat162_rn(make_float2(a, b));
    return *reinterpret_cast<unsigned*>(&t);
}

// sEX/sVl overlays on Y's k-half (rows 0..31), half-index addressing
__device__ __forceinline__ float& sEXat(unsigned short* sR, int ix) {
    return *(float*)(sR + ((ix >> 6) << 8) + ((ix & 63) << 1));
}
__device__ __forceinline__ float& sVLat(unsigned short* sR, int ix) {
    return *(float*)(sR + 4096 + ((ix >> 6) << 8) + ((ix & 63) << 1));
}

// ---------------------- init: cnt/0 ----------------------
__global__ void k_init0(int* __restrict__ cnt) {
    int i = blockIdx.x * 256 + threadIdx.x;
    if (i < NN) cnt[i] = 0;
}

// ---------- fused: hist (1250) + prep (5552) + zero Dg/Pg (2500) ----------
#define PRE_HIST 1250
#define PRE_PREP 5552
#define PRE_ZERO 2500
__global__ __launch_bounds__(256) void k_pre(
    const int* __restrict__ ei, int* __restrict__ cnt,
    const float* __restrict__ h,
    const float* __restrict__ kW1, const float* __restrict__ vW1,
    const float* __restrict__ kW2, const float* __restrict__ vW2,
    const float* __restrict__ qW1, const float* __restrict__ qW2,
    unsigned short* __restrict__ h_bf, unsigned short* __restrict__ Wt1,
    unsigned short* __restrict__ kW2t, unsigned short* __restrict__ vW2t,
    unsigned short* __restrict__ qW1t, unsigned short* __restrict__ qW2t,
    float* __restrict__ Dg, float* __restrict__ Pg)
{
    const int tid = threadIdx.x;
    int b = blockIdx.x;

    if (b < PRE_HIST) {                       // ---- histogram ----
        int e = b * 256 + tid;                // EE = 1250*256 exactly
        atomicAdd(&cnt[ei[EE + e]], 1);
        return;
    }
    b -= PRE_HIST;
    if (b < PRE_PREP) {                       // ---- prep ----
        int i = b * 256 + tid;
        if (i < NN * 128) { h_bf[i] = f2bf(h[i]); return; }
        int j = i - NN * 128;
        if (j < 256 * 352) {
            int n = j / 352, k = j % 352;
            float val = 0.f;
            if (k < 340) {
                int pk;
                if (k < 128)      pk = 84 + k;
                else if (k < 256) pk = 212 + (k - 128);
                else if (k < 260) pk = k - 256;
                else              pk = 4 + (k - 260);
                val = (n < 128) ? kW1[pk * 128 + n] : vW1[pk * 128 + (n - 128)];
            }
            Wt1[j] = f2bf(val); return;
        }
        j -= 256 * 352;
        if (j < 128 * 128) { int n = j >> 7, k = j & 127; kW2t[j] = f2bf(kW2[k * 128 + n]); return; }
        j -= 128 * 128;
        if (j < 16 * 128)  { int n = j >> 7, k = j & 127; vW2t[j] = f2bf(vW2[k * 16 + n]); return; }
        j -= 16 * 128;
        if (j < 128 * 128) { int n = j >> 7, k = j & 127; qW1t[j] = f2bf(qW1[k * 128 + n]); return; }
        j -= 128 * 128;
        if (j < 128 * 128) { int n = j >> 7, k = j & 127; qW2t[j] = f2bf(qW2[k * 128 + n]); return; }
        return;
    }
    b -= PRE_PREP;                            // ---- zero Dg/Pg ----
    int i = b * 256 + tid;
    if (i < NN * 16) Dg[i] = 0.f;
    else if (i < NN * 64) Pg[i - NN * 16] = 0.f;
}

// ---------------------- scan (wave-based) ----------------------
__global__ __launch_bounds__(1024) void k_scan(const int* __restrict__ cnt,
                                               int* __restrict__ cnt2) {
    __shared__ int wsum[16];
    const int t = threadIdx.x;
    const int lane = t & 63, w = t >> 6;
    int loc[10];
    int s = 0;
    #pragma unroll
    for (int i = 0; i < 10; ++i) {
        int idx = t * 10 + i;
        loc[i] = (idx < NN) ? cnt[idx] : 0;
        s += loc[i];
    }
    int sc = s;
    #pragma unroll
    for (int off = 1; off < 64; off <<= 1) {
        int v = __shfl_up(sc, off, 64);
        if (lane >= off) sc += v;
    }
    if (lane == 63) wsum[w] = sc;
    __syncthreads();
    if (w == 0) {
        int v = (lane < 16) ? wsum[lane] : 0;
        int c = v;
        #pragma unroll
        for (int off = 1; off < 16; off <<= 1) {
            int t2 = __shfl_up(c, off, 64);
            if (lane >= off) c += t2;
        }
        if (lane < 16) wsum[lane] = c - v;
    }
    __syncthreads();
    int run = wsum[w] + sc - s;
    #pragma unroll
    for (int i = 0; i < 10; ++i) {
        int idx = t * 10 + i;
        if (idx < NN) { cnt2[idx] = run; run += loc[i]; }
    }
}

// ---------- fused: place (1250) + MFMA q-MLP (157 blocks, 64 nodes each) ----------
#define PQ_PLACE 1250
#define PQ_QMLP  157
__global__ __launch_bounds__(256) void k_placeq(
    const int* __restrict__ ei, int* __restrict__ cnt2, int* __restrict__ perm,
    const unsigned short* __restrict__ h_bf,
    const unsigned short* __restrict__ qW1t, const float* __restrict__ qb1,
    const float* __restrict__ qg,  const float* __restrict__ qbt,
    const unsigned short* __restrict__ qW2t, const float* __restrict__ qb2,
    float* __restrict__ qout)
{
    __shared__ __align__(16) unsigned short sQ[64 * 128];
    __shared__ float2 sSt[4 * 64];
    const int tid = threadIdx.x;
    int b = blockIdx.x;

    if (b < PQ_PLACE) {                       // ---- place ----
        int e = b * 256 + tid;
        int slot = atomicAdd(&cnt2[ei[EE + e]], 1);
        perm[slot] = e;
        return;
    }
    b -= PQ_PLACE;                            // ---- q-MLP (MFMA) ----
    const int n0q = b * 64;
    const int lane = tid & 63, wv = tid >> 6, rA = lane & 15, kq = lane >> 4;

    // stage h_bf [64 rows][16 chunks] swizzled
    #pragma unroll
    for (int it = 0; it < 4; ++it) {
        int p = tid + it * 256;
        int r = p >> 4, c = p & 15;
        int node = n0q + r; if (node >= NN) node = NN - 1;
        uint4 v = *(const uint4*)(h_bf + node * 128 + c * 8);
        *(uint4*)(sQ + r * 128 + ((c ^ (r & 7)) << 3)) = v;
    }
    __syncthreads();

    const int nb = wv * 32;
    f32x4 zf = {0.f, 0.f, 0.f, 0.f};
    f32x4 acc[2][4];
    #pragma unroll
    for (int nf = 0; nf < 2; ++nf)
        #pragma unroll
        for (int ef = 0; ef < 4; ++ef) acc[nf][ef] = zf;

    for (int k0 = 0; k0 < 128; k0 += 32) {
        int cb = (k0 >> 3) + kq;
        short8 wf[2], kv[4];
        #pragma unroll
        for (int nf = 0; nf < 2; ++nf)
            wf[nf] = *(const short8*)(qW1t + (nb + nf * 16 + rA) * 128 + k0 + kq * 8);
        #pragma unroll
        for (int ef = 0; ef < 4; ++ef) {
            int r = ef * 16 + rA;
            kv[ef] = *(const short8*)(sQ + r * 128 + ((cb ^ (r & 7)) << 3));
        }
        #pragma unroll
        for (int nf = 0; nf < 2; ++nf)
            #pragma unroll
            for (int ef = 0; ef < 4; ++ef)
                acc[nf][ef] = __builtin_amdgcn_mfma_f32_16x16x32_bf16(wf[nf], kv[ef], acc[nf][ef], 0, 0, 0);
    }
    // bias
    #pragma unroll
    for (int nf = 0; nf < 2; ++nf) {
        f32x4 bb = *(const f32x4*)(qb1 + nb + nf * 16 + kq * 4);
        #pragma unroll
        for (int ef = 0; ef < 4; ++ef)
            #pragma unroll
            for (int j = 0; j < 4; ++j) acc[nf][ef][j] += bb[j];
    }
    // LN stats: per lane 8 cols per node-frag; reduce over kq then across waves
    float sm[4], sq2[4];
    #pragma unroll
    for (int ef = 0; ef < 4; ++ef) {
        float s = 0.f, s2 = 0.f;
        #pragma unroll
        for (int nf = 0; nf < 2; ++nf)
            #pragma unroll
            for (int j = 0; j < 4; ++j) { float v = acc[nf][ef][j]; s += v; s2 += v * v; }
        s  += __shfl_xor(s, 16, 64);  s  += __shfl_xor(s, 32, 64);
        s2 += __shfl_xor(s2, 16, 64); s2 += __shfl_xor(s2, 32, 64);
        sm[ef] = s; sq2[ef] = s2;
    }
    if (kq == 0) {
        #pragma unroll
        for (int ef = 0; ef < 4; ++ef)
            sSt[wv * 64 + ef * 16 + rA] = make_float2(sm[ef], sq2[ef]);
    }
    __syncthreads();

    // normalize + ReLU + pack -> Y overlay on sQ
    {
        f32x4 g4[2], b4[2];
        #pragma unroll
        for (int nf = 0; nf < 2; ++nf) {
            g4[nf] = *(const f32x4*)(qg  + nb + nf * 16 + kq * 4);
            b4[nf] = *(const f32x4*)(qbt + nb + nf * 16 + kq * 4);
        }
        #pragma unroll
        for (int ef = 0; ef < 4; ++ef) {
            int r = ef * 16 + rA;
            float ts = 0.f, ts2 = 0.f;
            #pragma unroll
            for (int w2 = 0; w2 < 4; ++w2) {
                float2 p = sSt[w2 * 64 + r];
                ts += p.x; ts2 += p.y;
            }
            float mu  = ts * (1.f / 128.f);
            float var = ts2 * (1.f / 128.f) - mu * mu;
            float rs  = rsqrtf(var + EPSf);
            #pragma unroll
            for (int nf = 0; nf < 2; ++nf) {
                float y[4];
                #pragma unroll
                for (int j = 0; j < 4; ++j) {
                    float f = (acc[nf][ef][j] - mu) * rs * g4[nf][j] + b4[nf][j];
                    y[j] = f > 0.f ? f : 0.f;
                }
                int col = nb + nf * 16 + kq * 4;
                int ch = col >> 3;
                uint2 pw; pw.x = pk2(y[0], y[1]); pw.y = pk2(y[2], y[3]);
                *(uint2*)(sQ + r * 128 + ((ch ^ (r & 7)) << 3) + (col & 7)) = pw;
            }
        }
    }
    __syncthreads();

    // layer 2
    f32x4 a2[2][4];
    #pragma unroll
    for (int nf = 0; nf < 2; ++nf)
        #pragma unroll
        for (int ef = 0; ef < 4; ++ef) a2[nf][ef] = zf;
    for (int k0 = 0; k0 < 128; k0 += 32) {
        int cb = (k0 >> 3) + kq;
        short8 wf[2], yv[4];
        #pragma unroll
        for (int nf = 0; nf < 2; ++nf)
            wf[nf] = *(const short8*)(qW2t + (nb + nf * 16 + rA) * 128 + k0 + kq * 8);
        #pragma unroll
        for (int ef = 0; ef < 4; ++ef) {
            int r = ef * 16 + rA;
            yv[ef] = *(const short8*)(sQ + r * 128 + ((cb ^ (r & 7)) << 3));
        }
        #pragma unroll
        for (int nf = 0; nf < 2; ++nf)
            #pragma unroll
            for (int ef = 0; ef < 4; ++ef)
                a2[nf][ef] = __builtin_amdgcn_mfma_f32_16x16x32_bf16(wf[nf], yv[ef], a2[nf][ef], 0, 0, 0);
    }
    #pragma unroll
    for (int nf = 0; nf < 2; ++nf) {
        f32x4 bb = *(const f32x4*)(qb2 + nb + nf * 16 + kq * 4);
        #pragma unroll
        for (int ef = 0; ef < 4; ++ef) {
            int node = n0q + ef * 16 + rA;
            if (node < NN) {
                f32x4 o;
                #pragma unroll
                for (int j = 0; j < 4; ++j) o[j] = a2[nf][ef][j] + bb[j];
                *(f32x4*)(qout + node * 128 + nb + nf * 16 + kq * 4) = o;
            }
        }
    }
}

// ------- per-slot MFMA kernel: 2-phase staging, q-prefetch, fused epilogue -------
__global__ __launch_bounds__(256, 3) void k_edge(
    const float* __restrict__ x, const unsigned short* __restrict__ h_bf,
    const float* __restrict__ ea, const int* __restrict__ ei,
    const int* __restrict__ perm,
    const unsigned short* __restrict__ Wt1,
    const float* __restrict__ kb1, const float* __restrict__ vb1,
    const float* __restrict__ kg, const float* __restrict__ kbt,
    const float* __restrict__ vg, const float* __restrict__ vbt,
    const unsigned short* __restrict__ kW2t, const float* __restrict__ kb2,
    const unsigned short* __restrict__ vW2t, const float* __restrict__ vb2,
    const float* __restrict__ q,
    float* __restrict__ Dg, float* __restrict__ Pg)
{
    __shared__ __align__(16) unsigned short sR[64 * 256];
    __shared__ float2 sStats[4 * 64];
    __shared__ float sEA[64 * 4];
    __shared__ float sRel[64 * 3];
    __shared__ float sDist[64];
    __shared__ int   sSrc[64], sDst[64];

    const int tid  = threadIdx.x;
    const int e0   = blockIdx.x * 64;
    const int lane = tid & 63;
    const int wv   = tid >> 6;
    const int rA   = lane & 15;
    const int kq   = lane >> 4;

    if (tid < 64) {
        int slot = e0 + tid;
        int e = perm[slot];
        int s = ei[e], d = ei[EE + e];
        sSrc[tid] = s; sDst[tid] = d;
        float rx = x[d*3+0] - x[s*3+0];
        float ry = x[d*3+1] - x[s*3+1];
        float rz = x[d*3+2] - x[s*3+2];
        sRel[tid*3+0] = rx; sRel[tid*3+1] = ry; sRel[tid*3+2] = rz;
        sDist[tid] = sqrtf(rx*rx + ry*ry + rz*rz);
        float4 eav = *(const float4*)(ea + e * 4);
        sEA[tid*4+0] = eav.x; sEA[tid*4+1] = eav.y;
        sEA[tid*4+2] = eav.z; sEA[tid*4+3] = eav.w;
    }
    __syncthreads();

    // ---- stage phase 1: k' 0..191
    #pragma unroll
    for (int it = 0; it < 6; ++it) {
        int p = tid + it * 256;
        int r = p / 24, cl = p % 24;
        int node = (cl < 16) ? sDst[r] : sSrc[r];
        int cc = cl & 15;
        uint4 v = *(const uint4*)(h_bf + node * 128 + cc * 8);
        *(uint4*)(sR + r * 192 + ((cl ^ (r & 7)) << 3)) = v;
    }
    __syncthreads();

    // ---- layer 1, phase A ----
    const int n0 = wv * 64;
    f32x4 zf = {0.f, 0.f, 0.f, 0.f};
    f32x4 acc[4][4];
    #pragma unroll
    for (int nf = 0; nf < 4; ++nf)
        #pragma unroll
        for (int ef = 0; ef < 4; ++ef) acc[nf][ef] = zf;

    for (int k0 = 0; k0 < 192; k0 += 32) {
        int clb = (k0 >> 3) + kq;
        short8 wfr[4], kv[4];
        #pragma unroll
        for (int nf = 0; nf < 4; ++nf)
            wfr[nf] = *(const short8*)(Wt1 + (n0 + nf * 16 + rA) * 352 + k0 + kq * 8);
        #pragma unroll
        for (int ef = 0; ef < 4; ++ef) {
            int r = ef * 16 + rA;
            kv[ef] = *(const short8*)(sR + r * 192 + ((clb ^ (r & 7)) << 3));
        }
        #pragma unroll
        for (int nf = 0; nf < 4; ++nf)
            #pragma unroll
            for (int ef = 0; ef < 4; ++ef)
                acc[nf][ef] = __builtin_amdgcn_mfma_f32_16x16x32_bf16(wfr[nf], kv[ef], acc[nf][ef], 0, 0, 0);
    }
    __syncthreads();

    // ---- stage phase 2 ----
    #pragma unroll
    for (int it = 0; it < 2; ++it) {
        int p = tid + it * 256;
        int r = p >> 3, cl = p & 7;
        uint4 v = *(const uint4*)(h_bf + sSrc[r] * 128 + (8 + cl) * 8);
        *(uint4*)(sR + r * 192 + ((cl ^ (r & 7)) << 3)) = v;
    }
    const float step  = 10.0f / 19.0f;
    const float coeff = -0.5f / (step * step);
    #pragma unroll
    for (int it = 0; it < 6; ++it) {
        int q4 = tid + it * 256;
        int r = q4 / 24, qi = q4 % 24;
        int i0 = qi * 4;
        float v[4];
        #pragma unroll
        for (int j = 0; j < 4; ++j) {
            int i = i0 + j;
            float val;
            if (i < 4) val = sEA[r*4 + i];
            else if (i < 84) {
                int f = (i - 4) / 20, gg = (i - 4) % 20;
                float dd = sDist[r] - (float)gg * step;
                val = sEA[r*4 + f] * __expf(coeff * dd * dd);
            } else val = 0.f;
            v[j] = val;
        }
        int cl = 8 + (i0 >> 3);
        uint2 pw; pw.x = pk2(v[0], v[1]); pw.y = pk2(v[2], v[3]);
        *(uint2*)(sR + r * 192 + ((cl ^ (r & 7)) << 3) + (i0 & 7)) = pw;
    }
    __syncthreads();

    // ---- layer 1, phase B ----
    for (int k0 = 192; k0 < 352; k0 += 32) {
        int clb = ((k0 - 192) >> 3) + kq;
        short8 wfr[4], kv[4];
        #pragma unroll
        for (int nf = 0; nf < 4; ++nf)
            wfr[nf] = *(const short8*)(Wt1 + (n0 + nf * 16 + rA) * 352 + k0 + kq * 8);
        #pragma unroll
        for (int ef = 0; ef < 4; ++ef) {
            int r = ef * 16 + rA;
            kv[ef] = *(const short8*)(sR + r * 192 + ((clb ^ (r & 7)) << 3));
        }
        #pragma unroll
        for (int nf = 0; nf < 4; ++nf)
            #pragma unroll
            for (int ef = 0; ef < 4; ++ef)
                acc[nf][ef] = __builtin_amdgcn_mfma_f32_16x16x32_bf16(wfr[nf], kv[ef], acc[nf][ef], 0, 0, 0);
    }

    // ---- bias add ----
    {
        const float* bsrc = (wv < 2) ? kb1 : vb1;
        int cb = (wv & 1) * 64;
        #pragma unroll
        for (int nf = 0; nf < 4; ++nf) {
            f32x4 bb = *(const f32x4*)(bsrc + cb + nf * 16 + kq * 4);
            #pragma unroll
            for (int ef = 0; ef < 4; ++ef)
                #pragma unroll
                for (int j = 0; j < 4; ++j) acc[nf][ef][j] += bb[j];
        }
    }

    // ---- in-register LN stats ----
    float sm[4], sq2[4];
    #pragma unroll
    for (int ef = 0; ef < 4; ++ef) {
        float s = 0.f, s2 = 0.f;
        #pragma unroll
        for (int nf = 0; nf < 4; ++nf)
            #pragma unroll
            for (int j = 0; j < 4; ++j) { float v = acc[nf][ef][j]; s += v; s2 += v * v; }
        sm[ef] = s; sq2[ef] = s2;
    }
    #pragma unroll
    for (int ef = 0; ef < 4; ++ef) {
        sm[ef]  += __shfl_xor(sm[ef], 16, 64);  sm[ef]  += __shfl_xor(sm[ef], 32, 64);
        sq2[ef] += __shfl_xor(sq2[ef], 16, 64); sq2[ef] += __shfl_xor(sq2[ef], 32, 64);
    }
    if (kq == 0) {
        #pragma unroll
        for (int ef = 0; ef < 4; ++ef)
            sStats[wv * 64 + ef * 16 + rA] = make_float2(sm[ef], sq2[ef]);
    }
    __syncthreads();

    // ---- normalize + ReLU + pack -> Y ----
    {
        const float* gp = (wv < 2) ? kg : vg;
        const float* bp = (wv < 2) ? kbt : vbt;
        f32x4 g4[4], b4[4];
        #pragma unroll
        for (int nf = 0; nf < 4; ++nf) {
            int cl = (wv & 1) * 64 + nf * 16 + kq * 4;
            g4[nf] = *(const f32x4*)(gp + cl);
            b4[nf] = *(const f32x4*)(bp + cl);
        }
        #pragma unroll
        for (int ef = 0; ef < 4; ++ef) {
            int e = ef * 16 + rA;
            float2 po = sStats[(wv ^ 1) * 64 + e];
            float mu  = (sm[ef] + po.x) * (1.f / 128.f);
            float var = (sq2[ef] + po.y) * (1.f / 128.f) - mu * mu;
            float rs  = rsqrtf(var + EPSf);
            #pragma unroll
            for (int nf = 0; nf < 4; ++nf) {
                float y[4];
                #pragma unroll
                for (int j = 0; j < 4; ++j) {
                    float f = (acc[nf][ef][j] - mu) * rs * g4[nf][j] + b4[nf][j];
                    y[j] = f > 0.f ? f : 0.f;
                }
                int col = n0 + nf * 16 + kq * 4;
                int ch = col >> 3;
                uint2 pw; pw.x = pk2(y[0], y[1]); pw.y = pk2(y[2], y[3]);
                *(uint2*)(sR + e * 256 + ((ch ^ (e & 7)) << 3) + (col & 7)) = pw;
            }
        }
    }
    __syncthreads();

    // ---- q prefetch (latency hidden under L2k MFMAs) ----
    const int n0k = wv * 32;
    int dloc[4];
    f32x4 qv[2][4];
    #pragma unroll
    for (int ef = 0; ef < 4; ++ef) dloc[ef] = sDst[ef * 16 + rA];
    #pragma unroll
    for (int nf2 = 0; nf2 < 2; ++nf2)
        #pragma unroll
        for (int ef = 0; ef < 4; ++ef)
            qv[nf2][ef] = *(const f32x4*)(q + dloc[ef] * 128 + n0k + nf2 * 16 + kq * 4);

    // ---- layer 2 (k) + logits ----
    float ps[2][4];
    {
        f32x4 a2[2][4];
        #pragma unroll
        for (int nf2 = 0; nf2 < 2; ++nf2)
            #pragma unroll
            for (int ef = 0; ef < 4; ++ef) a2[nf2][ef] = zf;
        for (int k0 = 0; k0 < 128; k0 += 32) {
            int cbase = (k0 >> 3) + kq;
            short8 wf2[2], yf[4];
            #pragma unroll
            for (int nf2 = 0; nf2 < 2; ++nf2)
                wf2[nf2] = *(const short8*)(kW2t + (n0k + nf2 * 16 + rA) * 128 + k0 + kq * 8);
            #pragma unroll
            for (int ef = 0; ef < 4; ++ef) {
                int r = ef * 16 + rA;
                yf[ef] = *(const short8*)(sR + r * 256 + ((cbase ^ (r & 7)) << 3));
            }
            #pragma unroll
            for (int nf2 = 0; nf2 < 2; ++nf2)
                #pragma unroll
                for (int ef = 0; ef < 4; ++ef)
                    a2[nf2][ef] = __builtin_amdgcn_mfma_f32_16x16x32_bf16(wf2[nf2], yf[ef], a2[nf2][ef], 0, 0, 0);
        }
        f32x4 bb2[2];
        bb2[0] = *(const f32x4*)(kb2 + n0k + kq * 4);
        bb2[1] = *(const f32x4*)(kb2 + n0k + 16 + kq * 4);

        #pragma unroll
        for (int nf2 = 0; nf2 < 2; ++nf2)
            #pragma unroll
            for (int ef = 0; ef < 4; ++ef) {
                float s = 0.f;
                #pragma unroll
                for (int j = 0; j < 4; ++j) s += qv[nf2][ef][j] * (a2[nf2][ef][j] + bb2[nf2][j]);
                ps[nf2][ef] = s;
            }
        #pragma unroll
        for (int nf2 = 0; nf2 < 2; ++nf2)
            #pragma unroll
            for (int ef = 0; ef < 4; ++ef)
                ps[nf2][ef] += __shfl_xor(ps[nf2][ef], 16, 64);
    }
    __syncthreads();   // Y k-half reads done -> overlay sEX/sVl

    // ---- write sEX; layer 2 (v) -> sVl ----
    {
        int h_base = wv * 4 + (kq >> 1);
        #pragma unroll
        for (int nf2 = 0; nf2 < 2; ++nf2)
            #pragma unroll
            for (int ef = 0; ef < 4; ++ef) {
                bool act = ((kq & 1) == 0) ? (ef < 2) : (ef >= 2);
                if (act) {
                    int e = ef * 16 + rA;
                    int hh = h_base + nf2 * 2;
                    sEXat(sR, hh * 64 + e) = __expf(ps[nf2][ef] * 0.35355339059327373f);
                }
            }
    }
    {
        f32x4 av = zf;
        int r = wv * 16 + rA;
        for (int k0 = 0; k0 < 128; k0 += 32) {
            int cbase = 16 + (k0 >> 3) + kq;
            short8 yv  = *(const short8*)(sR + r * 256 + ((cbase ^ (r & 7)) << 3));
            short8 wfv = *(const short8*)(vW2t + rA * 128 + k0 + kq * 8);
            av = __builtin_amdgcn_mfma_f32_16x16x32_bf16(wfv, yv, av, 0, 0, 0);
        }
        f32x4 bv = *(const f32x4*)(vb2 + kq * 4);
        #pragma unroll
        for (int j = 0; j < 4; ++j)
            sVLat(sR, (kq * 4 + j) * 64 + r) = av[j] + bv[j];
    }
    __syncthreads();

    // ---- segmented scan; atomics only at segment ends ----
    {
        const int s    = lane & 15;
        const int quad = lane >> 4;
        const int slot = wv * 16 + s;
        const int node = sDst[slot];

        bool fl = (s == 0) || (sDst[slot] != sDst[slot - 1]);
        unsigned long long bal = __ballot(fl);
        unsigned fb = (unsigned)((bal >> (quad * 16)) & 0xFFFFull);

        unsigned pre = fb & ((2u << s) - 1);
        int sstart = 31 - __clz(pre);

        float rx = sRel[slot * 3 + 0], ry = sRel[slot * 3 + 1], rz = sRel[slot * 3 + 2];
        float ex4[4], px[4], py[4], pz[4];
        #pragma unroll
        for (int j = 0; j < 4; ++j) {
            float exv = sEXat(sR, (quad * 4 + j) * 64 + slot);
            float vv  = sVLat(sR, (quad * 4 + j) * 64 + slot);
            float m = exv * vv;
            ex4[j] = exv; px[j] = m * rx; py[j] = m * ry; pz[j] = m * rz;
        }
        #pragma unroll
        for (int st = 1; st <= 8; st <<= 1) {
            bool take = (s - st >= sstart);
            #pragma unroll
            for (int j = 0; j < 4; ++j) {
                float t0 = __shfl_up(ex4[j], st, 16);
                float t1 = __shfl_up(px[j],  st, 16);
                float t2 = __shfl_up(py[j],  st, 16);
                float t3 = __shfl_up(pz[j],  st, 16);
                if (take) { ex4[j] += t0; px[j] += t1; py[j] += t2; pz[j] += t3; }
            }
        }
        bool isend = (s == 15) || ((fb >> (s + 1)) & 1u);
        if (isend) {
            #pragma unroll
            for (int j = 0; j < 4; ++j) {
                int hh = quad * 4 + j;
                atomicAdd(&Dg[node * 16 + hh], ex4[j]);
                atomicAdd(&Pg[node * 48 + 0 * 16 + hh], px[j]);
                atomicAdd(&Pg[node * 48 + 1 * 16 + hh], py[j]);
                atomicAdd(&Pg[node * 48 + 2 * 16 + hh], pz[j]);
            }
        }
    }
}

// ---------------------- finalize ----------------------
__global__ void k_fin(const float* __restrict__ Dg, const float* __restrict__ Pg,
                      float* __restrict__ out) {
    int n = blockIdx.x * 256 + threadIdx.x;
    if (n >= NN) return;
    float inv[16];
    #pragma unroll
    for (int hq = 0; hq < 4; ++hq) {
        f32x4 d = *(const f32x4*)(Dg + n * 16 + hq * 4);
        #pragma unroll
        for (int j = 0; j < 4; ++j) inv[hq * 4 + j] = (d[j] > 0.f) ? (1.f / d[j]) : 0.f;
    }
    #pragma unroll
    for (int c = 0; c < 3; ++c) {
        float s = 0.f;
        #pragma unroll
        for (int hq = 0; hq < 4; ++hq) {
            f32x4 p = *(const f32x4*)(Pg + n * 48 + c * 16 + hq * 4);
            #pragma unroll
            for (int j = 0; j < 4; ++j) s += p[j] * inv[hq * 4 + j];
        }
        out[n * 3 + c] = s * (1.f / 16.f);
    }
}

extern "C" void kernel_launch(void* const* d_in, const int* in_sizes, int n_in,
                              void* d_out, int out_size, void* d_ws, size_t ws_size,
                              hipStream_t stream) {
    const float* x   = (const float*)d_in[0];
    const float* h   = (const float*)d_in[1];
    const float* ea  = (const float*)d_in[2];
    const int*   ei  = (const int*)d_in[4];
    const float* kW1 = (const float*)d_in[5];
    const float* kb1 = (const float*)d_in[6];
    const float* kg  = (const float*)d_in[7];
    const float* kbt = (const float*)d_in[8];
    const float* kW2 = (const float*)d_in[9];
    const float* kb2 = (const float*)d_in[10];
    const float* vW1 = (const float*)d_in[11];
    const float* vb1 = (const float*)d_in[12];
    const float* vg  = (const float*)d_in[13];
    const float* vbt = (const float*)d_in[14];
    const float* vW2 = (const float*)d_in[15];
    const float* vb2 = (const float*)d_in[16];
    const float* qW1 = (const float*)d_in[17];
    const float* qb1 = (const float*)d_in[18];
    const float* qg  = (const float*)d_in[19];
    const float* qbt = (const float*)d_in[20];
    const float* qW2 = (const float*)d_in[21];
    const float* qb2 = (const float*)d_in[22];

    float* ws = (float*)d_ws;
    float* qbuf = ws;                            // N*128 = 1,280,000 w
    float* Dg   = ws + 1280000;                  // N*16
    float* Pg   = ws + 1440000;                  // N*48
    unsigned short* h_bf = (unsigned short*)(ws + 1920000);   // N*128 halves
    unsigned short* Wt1  = (unsigned short*)(ws + 2560000);   // 256*352 halves
    unsigned short* kW2t = (unsigned short*)(ws + 2605056);   // 128*128 halves
    unsigned short* vW2t = (unsigned short*)(ws + 2613248);   // 16*128 halves
    unsigned short* qW1t = (unsigned short*)(ws + 2614272);   // 128*128 halves
    unsigned short* qW2t = (unsigned short*)(ws + 2622464);   // 128*128 halves
    int* cnt  = (int*)(ws + 2630656);            // N
    int* cnt2 = (int*)(ws + 2640656);            // N
    int* perm = (int*)(ws + 2650656);            // E
    float* out = (float*)d_out;

    hipLaunchKernelGGL(k_init0, dim3(40),   dim3(256),  0, stream, cnt);
    hipLaunchKernelGGL(k_pre,   dim3(PRE_HIST + PRE_PREP + PRE_ZERO), dim3(256), 0, stream,
                       ei, cnt, h, kW1, vW1, kW2, vW2, qW1, qW2,
                       h_bf, Wt1, kW2t, vW2t, qW1t, qW2t, Dg, Pg);
    hipLaunchKernelGGL(k_scan,  dim3(1),    dim3(1024), 0, stream, cnt, cnt2);
    hipLaunchKernelGGL(k_placeq, dim3(PQ_PLACE + PQ_QMLP), dim3(256), 0, stream,
                       ei, cnt2, perm, h_bf, qW1t, qb1, qg, qbt, qW2t, qb2, qbuf);
    hipLaunchKernelGGL(k_edge,  dim3(5000), dim3(256),  0, stream,
                       x, h_bf, ea, ei, perm, Wt1,
                       kb1, vb1, kg, kbt, vg, vbt,
                       kW2t, kb2, vW2t, vb2,
                       qbuf, Dg, Pg);
    hipLaunchKernelGGL(k_fin,   dim3(40),   dim3(256),  0, stream, Dg, Pg, out);
}